// Round 2
// baseline (403.763 us; speedup 1.0000x reference)
//
#include <hip/hip_runtime.h>
#include <stdint.h>

// ---------------- Problem constants ----------------
#define T_TOK 8192
#define DDIM  1024
#define NEXP  16
#define MAXT  208   // 64 shared tiles + worst-case 144 expert tiles

typedef unsigned short u16;
typedef __attribute__((ext_vector_type(8))) short v8s;   // 8 x bf16 (4 VGPRs)
typedef __attribute__((ext_vector_type(4))) float v4f;   // 4 x f32 acc

// fp32 -> bf16 round-to-nearest-even
__device__ __forceinline__ u16 f2bf(float f) {
  union { float f; unsigned u; } v; v.f = f;
  unsigned r = v.u + 0x7fffu + ((v.u >> 16) & 1u);
  return (u16)(r >> 16);
}

// async global->LDS, 16B per lane. LDS dest = wave-uniform base + lane*16.
__device__ __forceinline__ void gload_lds16(const u16* gsrc, u16* ldst) {
  typedef __attribute__((address_space(1))) const void GV;
  typedef __attribute__((address_space(3))) void LV;
  __builtin_amdgcn_global_load_lds((GV*)(uintptr_t)gsrc, (LV*)(uintptr_t)ldst, 16, 0, 0);
}

// ---------------- fp32 -> bf16 conversions ----------------
__global__ __launch_bounds__(256) void k_cvt4(const float4* __restrict__ in,
                                              ushort4* __restrict__ out, int n4) {
  int i = blockIdx.x * 256 + threadIdx.x;
  if (i >= n4) return;
  float4 v = in[i];
  ushort4 o; o.x = f2bf(v.x); o.y = f2bf(v.y); o.z = f2bf(v.z); o.w = f2bf(v.w);
  out[i] = o;
}

// Wc[h,d] = sw[h,d] + sw[1024+h,d]
__global__ __launch_bounds__(256) void k_cvt_shared(const float4* __restrict__ sw,
                                                    ushort4* __restrict__ out, int n4) {
  int i = blockIdx.x * 256 + threadIdx.x;
  if (i >= n4) return;
  float4 a = sw[i];
  float4 b = sw[i + n4];
  ushort4 o;
  o.x = f2bf(a.x + b.x); o.y = f2bf(a.y + b.y);
  o.z = f2bf(a.z + b.z); o.w = f2bf(a.w + b.w);
  out[i] = o;
}

// ---------------- Router (unchanged; passed R1) ----------------
__global__ __launch_bounds__(256) void k_router(const float* __restrict__ x,
                                                const float* __restrict__ rw,
                                                int* __restrict__ topkI,
                                                float* __restrict__ topkW,
                                                int* __restrict__ counts,
                                                float* __restrict__ piSum) {
  __shared__ float lds_pi[NEXP];
  __shared__ int   lds_cnt[NEXP];
  int tid = threadIdx.x;
  if (tid < NEXP) { lds_pi[tid] = 0.f; lds_cnt[tid] = 0; }
  __syncthreads();
  int lane = tid & 63, wave = tid >> 6;

  for (int ti = 0; ti < 8; ++ti) {
    int t = blockIdx.x * 32 + wave * 8 + ti;
    const float* xr = x + (size_t)t * DDIM;
    float xv[16];
#pragma unroll
    for (int i = 0; i < 16; ++i) xv[i] = xr[i * 64 + lane];
    float lg[NEXP];
#pragma unroll
    for (int e = 0; e < NEXP; ++e) {
      const float* wr = rw + (size_t)e * DDIM;
      float p = 0.f;
#pragma unroll
      for (int i = 0; i < 16; ++i) p += xv[i] * wr[i * 64 + lane];
#pragma unroll
      for (int off = 32; off > 0; off >>= 1) p += __shfl_xor(p, off);
      lg[e] = p;
    }
    float mx = lg[0];
#pragma unroll
    for (int e = 1; e < NEXP; ++e) mx = fmaxf(mx, lg[e]);
    float sum = 0.f;
#pragma unroll
    for (int e = 0; e < NEXP; ++e) sum += __expf(lg[e] - mx);
    float v0 = lg[0]; int i0 = 0;
#pragma unroll
    for (int e = 1; e < NEXP; ++e) if (lg[e] > v0) { v0 = lg[e]; i0 = e; }
    float v1 = -3.0e38f; int i1 = 0;
#pragma unroll
    for (int e = 0; e < NEXP; ++e) if (e != i0 && lg[e] > v1) { v1 = lg[e]; i1 = e; }
    float e1 = __expf(v1 - v0);
    float w0 = 1.f / (1.f + e1);
    float w1 = e1 / (1.f + e1);
    if (lane == 0) {
      topkI[2 * t] = i0; topkI[2 * t + 1] = i1;
      topkW[2 * t] = w0; topkW[2 * t + 1] = w1;
      atomicAdd(&lds_cnt[i0], 1); atomicAdd(&lds_cnt[i1], 1);
    }
#pragma unroll
    for (int e = 0; e < NEXP; ++e)
      if (lane == e) atomicAdd(&lds_pi[e], __expf(lg[e] - mx) / sum);
  }
  __syncthreads();
  if (tid < NEXP) {
    atomicAdd(&counts[tid], lds_cnt[tid]);
    atomicAdd(&piSum[tid], lds_pi[tid]);
  }
}

// ---------------- Finalize: offsets, COMBINED tile list, aux loss ----------------
__global__ void k_finalize(const int* __restrict__ counts, const float* __restrict__ piSum,
                           int* __restrict__ offs, int* __restrict__ meta,
                           int* __restrict__ ntile, int* __restrict__ cursor,
                           float* __restrict__ outAux) {
  if (threadIdx.x != 0) return;
  int off = 0;
  for (int e = 0; e < NEXP; ++e) { offs[e] = off; off += counts[e]; }
  offs[NEXP] = off;
  int nt = 0;
  // shared-expert tiles first (e = NEXP, identity rows)
  for (int rs = 0; rs < T_TOK; rs += 128) { meta[2 * nt] = NEXP; meta[2 * nt + 1] = rs; ++nt; }
  // routed-expert tiles
  for (int e = 0; e < NEXP; ++e) {
    for (int rs = 0; rs < counts[e]; rs += 128) { meta[2 * nt] = e; meta[2 * nt + 1] = rs; ++nt; }
    cursor[e] = 0;
  }
  ntile[0] = nt;
  float aux = 0.f;
  for (int e = 0; e < NEXP; ++e)
    aux += (piSum[e] / (float)T_TOK) * ((float)counts[e] / (float)T_TOK);
  outAux[0] = aux;
}

// ---------------- Scatter token-expert pairs into buckets ----------------
__global__ __launch_bounds__(256) void k_scatter(const int* __restrict__ topkI,
                                                 const float* __restrict__ topkW,
                                                 const int* __restrict__ offs,
                                                 int* __restrict__ cursor,
                                                 int* __restrict__ rowTok,
                                                 float* __restrict__ rowW) {
  __shared__ int lcnt[NEXP], lbase[NEXP];
  int tid = threadIdx.x;
  if (tid < NEXP) lcnt[tid] = 0;
  __syncthreads();
  int p = blockIdx.x * 256 + tid;
  int e = topkI[p];
  int myLocal = atomicAdd(&lcnt[e], 1);
  __syncthreads();
  if (tid < NEXP) lbase[tid] = atomicAdd(&cursor[tid], lcnt[tid]);
  __syncthreads();
  int dst = offs[e] + lbase[e] + myLocal;
  rowTok[dst] = p >> 1;
  rowW[dst] = topkW[p];
}

// ---------------- Fused grouped GEMM: 128x128, BK=32, 2-phase pipeline ----------------
// LDS layout per tile (16B units): pos16 = kc*128 + row, kc in 0..3 (8 bf16 of K each).
// Staging: thread tid issues 2 loads per matrix: (kc0=tid>>7, row=tid&127) and kc0+2.
//   Wave-uniform LDS bases: buf + wave*512 u16 and buf + 2048 + wave*512 u16 (linear in tid).
// Reader: lane needs row R, K-chunk q=lane>>4 -> u16 offset (q*128+R)*8 -> 256B-contiguous
//   per 16-lane group -> 2 lanes/bank -> conflict-free.
__global__ __launch_bounds__(256, 4) void k_gemm(const u16* __restrict__ xb,
                                                 const u16* __restrict__ wb,
                                                 const int* __restrict__ meta,
                                                 const int* __restrict__ ntile,
                                                 const int* __restrict__ offs,
                                                 const int* __restrict__ rowTok,
                                                 const float* __restrict__ rowW,
                                                 float* __restrict__ out) {
  __shared__ u16 As[2][4096];
  __shared__ u16 Bs[2][4096];
  int tid = threadIdx.x;
  int ti = blockIdx.x;
  if (ti >= ntile[0]) return;
  int lane = tid & 63, wave = tid >> 6;
  int tileN = blockIdx.y;

  int e = meta[2 * ti], rowStart = meta[2 * ti + 1];
  int offBase = 0, cnt;
  int srow = tid & 127;     // tile-local row this thread stages
  int kc8 = (tid >> 7) * 8; // u16 offset of first K-chunk (0 or 8); second at +16
  int tok;
  if (e == NEXP) {
    cnt = T_TOK; tok = rowStart + srow;
  } else {
    offBase = offs[e]; cnt = offs[e + 1] - offBase;
    tok = rowTok[offBase + min(rowStart + srow, cnt - 1)];
  }
  const u16* aRow = xb + (size_t)tok * DDIM + kc8;
  const u16* bRow = wb + (size_t)e * (DDIM * DDIM) + (size_t)(tileN * 128 + srow) * DDIM + kc8;

  v4f acc[4][4];
#pragma unroll
  for (int m = 0; m < 4; ++m)
#pragma unroll
    for (int n = 0; n < 4; ++n) acc[m][n] = (v4f)0.f;

  int wm = (wave >> 1) * 64, wn = (wave & 1) * 64;
  int rsel = lane & 15;
  int q = lane >> 4;

#define STAGE(buf, k0)                                              \
  do {                                                              \
    gload_lds16(aRow + (k0),      &As[buf][wave * 512]);            \
    gload_lds16(aRow + (k0) + 16, &As[buf][2048 + wave * 512]);     \
    gload_lds16(bRow + (k0),      &Bs[buf][wave * 512]);            \
    gload_lds16(bRow + (k0) + 16, &Bs[buf][2048 + wave * 512]);     \
  } while (0)

  // prologue
  STAGE(0, 0);
  __syncthreads();

  int cur = 0;
  for (int t = 0; t < DDIM / 32; ++t) {
    if (t + 1 < DDIM / 32) STAGE(cur ^ 1, (t + 1) * 32);  // prefetch next K-tile

    v8s af[4], bfr[4];
#pragma unroll
    for (int m = 0; m < 4; ++m)
      af[m] = *(const v8s*)&As[cur][(q * 128 + wm + m * 16 + rsel) * 8];
#pragma unroll
    for (int n = 0; n < 4; ++n)
      bfr[n] = *(const v8s*)&Bs[cur][(q * 128 + wn + n * 16 + rsel) * 8];
#pragma unroll
    for (int m = 0; m < 4; ++m)
#pragma unroll
      for (int n = 0; n < 4; ++n)
        acc[m][n] = __builtin_amdgcn_mfma_f32_16x16x32_bf16(af[m], bfr[n], acc[m][n], 0, 0, 0);

    __syncthreads();  // drains vmcnt (next tile staged) + lgkmcnt (our reads done)
    cur ^= 1;
  }
#undef STAGE

  // epilogue: C/D layout col=lane&15, row=(lane>>4)*4+j; out pre-zeroed -> all atomicAdd
  int colBase = tileN * 128 + wn + rsel;
#pragma unroll
  for (int m = 0; m < 4; ++m) {
    int rloc = rowStart + wm + m * 16 + q * 4;
#pragma unroll
    for (int j = 0; j < 4; ++j) {
      int r = rloc + j;
      if (r < cnt) {
        int t; float w;
        if (e == NEXP) { t = r; w = 1.f; }
        else { t = rowTok[offBase + r]; w = rowW[offBase + r]; }
        float* orow = out + (size_t)t * DDIM;
#pragma unroll
        for (int n = 0; n < 4; ++n)
          atomicAdd(orow + colBase + n * 16, w * acc[m][n][j]);
      }
    }
  }
}

// ---------------- launch ----------------
extern "C" void kernel_launch(void* const* d_in, const int* in_sizes, int n_in,
                              void* d_out, int out_size, void* d_ws, size_t ws_size,
                              hipStream_t stream) {
  const float* feat = (const float*)d_in[0];  // [8192][1024]
  const float* rw   = (const float*)d_in[1];  // [16][1024]
  const float* sw   = (const float*)d_in[2];  // [2048][1024]
  const float* ew   = (const float*)d_in[3];  // [16][1024][1024]
  float* out = (float*)d_out;                 // [8192*1024] + aux at [8388608]
  char* ws = (char*)d_ws;

  // ws layout (~52.7 MB)
  u16* xb = (u16*)(ws + 0);                         // 16 MB
  u16* wb = (u16*)(ws + 16777216);                  // 17 x 2 MB
  char* smallBase = ws + 52428800;
  int*   counts = (int*)(smallBase + 0);
  float* piSum  = (float*)(smallBase + 64);
  int*   cursor = (int*)(smallBase + 128);
  int*   ntile  = (int*)(smallBase + 192);
  int*   topkI  = (int*)(ws + 52429056);
  float* topkW  = (float*)(ws + 52494592);
  int*   offs   = (int*)(ws + 52560128);
  int*   rowTok = (int*)(ws + 52560256);
  float* rowW   = (float*)(ws + 52625792);
  int*   meta   = (int*)(ws + 52691328);

  hipMemsetAsync(smallBase, 0, 256, stream);
  hipMemsetAsync(out, 0, (size_t)out_size * sizeof(float), stream);

  k_cvt4<<<8192, 256, 0, stream>>>((const float4*)feat, (ushort4*)xb, 2097152);
  k_cvt4<<<16384, 256, 0, stream>>>((const float4*)ew, (ushort4*)wb, 4194304);
  k_cvt_shared<<<1024, 256, 0, stream>>>((const float4*)sw,
                                         (ushort4*)(wb + (size_t)NEXP * DDIM * DDIM), 262144);

  k_router<<<256, 256, 0, stream>>>(feat, rw, topkI, topkW, counts, piSum);
  k_finalize<<<1, 64, 0, stream>>>(counts, piSum, offs, meta, ntile, cursor, out + 8388608);
  k_scatter<<<64, 256, 0, stream>>>(topkI, topkW, offs, cursor, rowTok, rowW);

  dim3 gFused(MAXT, 8);
  k_gemm<<<gFused, 256, 0, stream>>>(xb, wb, meta, ntile, offs, rowTok, rowW, out);
}